// Round 6
// baseline (92.439 us; speedup 1.0000x reference)
//
#include <hip/hip_runtime.h>

#define D_M     64
#define L_OBS   256
#define ALPHA   256
#define D_H     256
#define D_V     64
#define N_HEADS 8

// ---------------------------------------------------------------------------
// Kernel 1: prep. Blocks 0..63: per-row imputation. Blocks 64..191: per-(h,
// 16-a-chunk) fold: Qa = theta_a . wq^T + wq_b, then QW[d][a] = Qa . wk[.][d].
// (All a-row-constant score terms are dropped: softmax is shift-invariant.)
// ---------------------------------------------------------------------------
__global__ __launch_bounds__(256) void prep_kernel(
    const float* __restrict__ x_ts, const float* __restrict__ t_ts,
    const float* __restrict__ gm,
    const float* __restrict__ t2v_w, const float* __restrict__ t2v_phi,
    const float* __restrict__ wq_w, const float* __restrict__ wq_b,
    const float* __restrict__ wk_w,
    float* __restrict__ regular, float* __restrict__ QWbuf)
{
    const int tid = threadIdx.x;

    __shared__ int   last[ALPHA];
    __shared__ float vals[ALPHA];
    __shared__ int   pos[ALPHA];
    __shared__ __align__(16) float wq_s[D_V][68];
    __shared__ __align__(16) float thA[16][68];
    __shared__ __align__(16) float QaT[16][68];

    if (blockIdx.x < D_M) {
        // ---------------- imputation ----------------
        const int m = blockIdx.x;
        const int l = tid;
        last[l] = -1;
        __syncthreads();
        float x = x_ts[m * L_OBS + l];
        float t = t_ts[m * L_OBS + l];
        bool valid = (x == x) && (t >= 0.0f);
        int idx = (int)t;
        if (valid && idx < ALPHA) atomicMax(&last[idx], l);
        __syncthreads();
        int li = last[l];
        vals[l] = (li >= 0) ? x_ts[m * L_OBS + li] : 0.0f;
        pos[l]  = (li >= 0) ? l : -1;
        __syncthreads();
        for (int off = 1; off < ALPHA; off <<= 1) {
            int v = (l >= off) ? pos[l - off] : -1;
            __syncthreads();
            if (v > pos[l]) pos[l] = v;
            __syncthreads();
        }
        int lp = pos[l];
        regular[m * ALPHA + l] = (lp >= 0) ? vals[lp] : gm[m];
    } else {
        // ---------------- weight fold + QW for 16 a ----------------
        const int p  = blockIdx.x - D_M;   // 0..127
        const int h  = p >> 4;
        const int a0 = (p & 15) * 16;

        {
            const float4* w4 = (const float4*)(wq_w + h * D_V * D_V);
            #pragma unroll
            for (int i = 0; i < 4; i++) {
                int f = i * 256 + tid;
                float4 v = w4[f];
                int e = f >> 4, c = (f & 15) * 4;
                *(float4*)&wq_s[e][c] = v;
            }
        }
        {
            int al = tid >> 4, j0 = (tid & 15) * 4;
            float tv = (float)(a0 + al);
            #pragma unroll
            for (int j = 0; j < 4; j++) {
                int d = j0 + j;
                float f = t2v_w[h * D_V + d] * tv + t2v_phi[h * D_V + d];
                thA[al][d] = (d == 0) ? f : __sinf(f);
            }
        }
        __syncthreads();

        // Phase A: QaT[a][e] = thA[a] . wq_s[e] + wq_b[e]
        {
            const int e  = tid >> 2;
            const int ap = tid & 3;
            float accA[4] = {0.f, 0.f, 0.f, 0.f};
            const float4* wrow = (const float4*)&wq_s[e][0];
            #pragma unroll
            for (int j = 0; j < 16; j++) {
                float4 w = wrow[j];
                #pragma unroll
                for (int k = 0; k < 4; k++) {
                    float4 tv = *(const float4*)&thA[ap + 4 * k][j * 4];
                    accA[k] += w.x * tv.x + w.y * tv.y + w.z * tv.z + w.w * tv.w;
                }
            }
            float bq = wq_b[h * D_V + e];
            #pragma unroll
            for (int k = 0; k < 4; k++) QaT[ap + 4 * k][e] = accA[k] + bq;
        }
        __syncthreads();

        // Phase B: QW[d][a] = sum_e QaT[a][e] * wk_w[h][e][d]
        {
            const int d  = tid >> 2;
            const int ap = tid & 3;
            float accB[4] = {0.f, 0.f, 0.f, 0.f};
            #pragma unroll 4
            for (int e4 = 0; e4 < 16; e4++) {
                const float* wkp = &wk_w[(h * D_V + e4 * 4) * D_V + d];
                float w0 = wkp[0];
                float w1 = wkp[D_V];
                float w2 = wkp[2 * D_V];
                float w3 = wkp[3 * D_V];
                #pragma unroll
                for (int k = 0; k < 4; k++) {
                    float4 qv = *(const float4*)&QaT[ap + 4 * k][e4 * 4];
                    accB[k] += qv.x * w0 + qv.y * w1 + qv.z * w2 + qv.w * w3;
                }
            }
            #pragma unroll
            for (int k = 0; k < 4; k++)
                QWbuf[h * D_V * ALPHA + d * ALPHA + a0 + ap + 4 * k] = accB[k];
        }
    }
}

// ---------------------------------------------------------------------------
// Kernel 2: fused mTAND attention with VALID-OBSERVATION COMPACTION.
// Block = 128 thr per (a-half, m, h); grid (2, 64, 8) = 1024 blocks, 3/CU.
// Invalid obs (mask -> exp underflows to exactly 0, x_safe=0) are dropped by
// a ballot/popc prefix compaction; the l-loop runs ceil(Lv/64) supertiles
// (E[Lv]=128 -> ~2x less score work). Padded tail entries get -1e9 mask and
// x=0, reproducing the reference f32 result exactly.
// QW slab (32KB) + theta tile (16KB) in LDS; 8a x 8l register tile (64 acc,
// fits any occupancy); all LDS reads <=2-way/bank (free). Lane-local online
// softmax in exp2 domain, one 8-lane merge at the end.
// LDS ~= 51 KB -> 3 blocks/CU.
// ---------------------------------------------------------------------------
__global__ __launch_bounds__(128) void attn_fused_kernel(
    const float* __restrict__ x_ts, const float* __restrict__ t_ts,
    const float* __restrict__ t2v_w, const float* __restrict__ t2v_phi,
    const float* __restrict__ QWbuf, float* __restrict__ interp)
{
    const int ah  = blockIdx.x;          // a-half (0/1)
    const int m   = blockIdx.y;
    const int h   = blockIdx.z;
    const int tid = threadIdx.x;         // 0..127
    const int a0  = ah * 128;

    __shared__ __align__(16) float QWs[D_V][128];   // 32 KiB [d][a-a0]
    __shared__ __align__(16) float tht[D_V][64];    // 16 KiB [d][lc]
    __shared__ __align__(16) float xc[L_OBS];       // compacted x
    __shared__ __align__(16) float tc[L_OBS];       // compacted t
    __shared__ float t2vw_s[D_V], t2vp_s[D_V];
    __shared__ int   cnt_s[4];                      // [batch*2 + wave]

    // init compacted arrays to padding values (t=0 -> harmless, masked)
    xc[tid] = 0.f; xc[tid + 128] = 0.f;
    tc[tid] = 0.f; tc[tid + 128] = 0.f;
    if (tid < D_V) t2vw_s[tid] = t2v_w[h * D_V + tid];
    else           t2vp_s[tid - D_V] = t2v_phi[h * D_V + tid - D_V];

    // stage QW slab: QWs[d][c] <- QWbuf[h][d][a0+c]
    {
        const float4* src = (const float4*)(QWbuf + h * D_V * ALPHA);
        float4* dst = (float4*)&QWs[0][0];
        #pragma unroll
        for (int i = 0; i < 16; i++) {
            int f = i * 128 + tid;      // 0..2047
            int d = f >> 5, c = f & 31;
            dst[d * 32 + c] = src[d * 64 + (a0 >> 2) + c];
        }
    }

    // load both obs batches, compute valid
    float x0 = x_ts[m * L_OBS + tid];
    float t0 = t_ts[m * L_OBS + tid];
    float x1 = x_ts[m * L_OBS + tid + 128];
    float t1 = t_ts[m * L_OBS + tid + 128];
    bool v0 = (x0 == x0) && (t0 >= 0.0f);
    bool v1 = (x1 == x1) && (t1 >= 0.0f);

    const int wv = tid >> 6;             // wave 0/1
    const int ln = tid & 63;
    unsigned long long lm = (1ull << ln) - 1ull;
    unsigned long long b0 = __ballot(v0);
    unsigned long long b1 = __ballot(v1);
    if (ln == 0) {
        cnt_s[0 * 2 + wv] = __popcll(b0);
        cnt_s[2 + wv]     = __popcll(b1);
    }
    __syncthreads();   // also covers xc/tc init + QW staging visibility

    const int c00 = cnt_s[0], c10 = cnt_s[1], c01 = cnt_s[2], c11 = cnt_s[3];
    const int Lv  = c00 + c10 + c01 + c11;
    // scatter (group order: (w0,b0),(w1,b0),(w0,b1),(w1,b1))
    {
        int base0 = (wv == 0) ? 0 : c00;
        int base1 = c00 + c10 + ((wv == 0) ? 0 : c01);
        if (v0) { int p = base0 + __popcll(b0 & lm); xc[p] = x0; tc[p] = t0; }
        if (v1) { int p = base1 + __popcll(b1 & lm); xc[p] = x1; tc[p] = t1; }
    }
    __syncthreads();

    const int nst = (Lv > 0) ? ((Lv + 63) >> 6) : 1;
    const int ta  = tid >> 3;    // 16 groups x 8 a
    const int tl  = tid & 7;     // 8 groups x 8 l
    const float SCALE2 = 0.18033688011112042f;  // 0.125 * log2(e)

    float mrun[8], ssum[8], axs[8];
    #pragma unroll
    for (int i = 0; i < 8; i++) { mrun[i] = -3.0e38f; ssum[i] = 0.f; axs[i] = 0.f; }

    const int lloc   = tid & 63;
    const int dbase  = (tid >> 6) * 32;

    for (int st = 0; st < nst; st++) {
        // ---- P1: theta tile [64 d][64 lc] ----
        {
            float tval = tc[st * 64 + lloc];
            #pragma unroll
            for (int dd = 0; dd < 32; dd++) {
                int d = dbase + dd;
                float f = t2vw_s[d] * tval + t2vp_s[d];
                tht[d][lloc] = (d == 0) ? f : __sinf(f);
            }
        }
        __syncthreads();
        // ---- P3: 8a x 8l over d, both operands LDS ----
        float acc[8][8];
        #pragma unroll
        for (int i = 0; i < 8; i++)
            #pragma unroll
            for (int j = 0; j < 8; j++) acc[i][j] = 0.f;
        #pragma unroll 4
        for (int d = 0; d < D_V; d++) {
            float4 q0 = *(const float4*)&QWs[d][ta * 8];
            float4 q1 = *(const float4*)&QWs[d][ta * 8 + 4];
            float4 t0v = *(const float4*)&tht[d][tl * 8];
            float4 t1v = *(const float4*)&tht[d][tl * 8 + 4];
            float qa[8] = {q0.x, q0.y, q0.z, q0.w, q1.x, q1.y, q1.z, q1.w};
            float tb[8] = {t0v.x, t0v.y, t0v.z, t0v.w, t1v.x, t1v.y, t1v.z, t1v.w};
            #pragma unroll
            for (int i = 0; i < 8; i++)
                #pragma unroll
                for (int j = 0; j < 8; j++)
                    acc[i][j] = fmaf(qa[i], tb[j], acc[i][j]);
        }
        // ---- online softmax update (lane-local) ----
        float xv[8], mk[8];
        {
            int lb = st * 64 + tl * 8;
            float4 a0v = *(const float4*)&xc[lb];
            float4 a1v = *(const float4*)&xc[lb + 4];
            xv[0]=a0v.x; xv[1]=a0v.y; xv[2]=a0v.z; xv[3]=a0v.w;
            xv[4]=a1v.x; xv[5]=a1v.y; xv[6]=a1v.z; xv[7]=a1v.w;
            #pragma unroll
            for (int j = 0; j < 8; j++)
                mk[j] = (lb + j < Lv) ? 0.0f : -1.0e9f;
        }
        #pragma unroll
        for (int i = 0; i < 8; i++) {
            float s[8];
            #pragma unroll
            for (int j = 0; j < 8; j++) s[j] = fmaf(acc[i][j], SCALE2, mk[j]);
            float tmax = s[0];
            #pragma unroll
            for (int j = 1; j < 8; j++) tmax = fmaxf(tmax, s[j]);
            float mnew = fmaxf(mrun[i], tmax);
            float scl = __builtin_amdgcn_exp2f(mrun[i] - mnew);
            float ps = 0.f, px = 0.f;
            #pragma unroll
            for (int j = 0; j < 8; j++) {
                float pv = __builtin_amdgcn_exp2f(s[j] - mnew);
                ps += pv;
                px = fmaf(pv, xv[j], px);
            }
            ssum[i] = fmaf(ssum[i], scl, ps);
            axs[i]  = fmaf(axs[i],  scl, px);
            mrun[i] = mnew;
        }
        __syncthreads();  // tht overwrite guard for next supertile
    }

    // ---- merge across the 8 tl lanes, write interp [a][m][h] ----
    #pragma unroll
    for (int i = 0; i < 8; i++) {
        float m0 = mrun[i];
        m0 = fmaxf(m0, __shfl_xor(m0, 1));
        m0 = fmaxf(m0, __shfl_xor(m0, 2));
        m0 = fmaxf(m0, __shfl_xor(m0, 4));
        float f = __builtin_amdgcn_exp2f(mrun[i] - m0);
        float S = ssum[i] * f;
        float A = axs[i] * f;
        S += __shfl_xor(S, 1); A += __shfl_xor(A, 1);
        S += __shfl_xor(S, 2); A += __shfl_xor(A, 2);
        S += __shfl_xor(S, 4); A += __shfl_xor(A, 4);
        if (tl == 0)
            interp[(a0 + ta * 8 + i) * (D_M * N_HEADS) + m * N_HEADS + h] = A / S;
    }
}

// ---------------------------------------------------------------------------
// Kernel 3: fused e_imp + e_attn + gate MLP + output. Block per a, 256 thr.
// ---------------------------------------------------------------------------
__global__ __launch_bounds__(256) void final_kernel(
    const float* __restrict__ regular, const float* __restrict__ interp,
    const float* __restrict__ conv_w, const float* __restrict__ conv_b,
    const float* __restrict__ proj_w, const float* __restrict__ proj_b,
    const float* __restrict__ g1_w, const float* __restrict__ g1_b,
    const float* __restrict__ g2_w, const float* __restrict__ g2_b,
    float* __restrict__ out)
{
    const int a = blockIdx.x;
    const int tid = threadIdx.x;
    __shared__ float isum_s[N_HEADS];
    __shared__ __align__(16) float col[D_M];
    __shared__ __align__(16) float c_s[2 * D_H];
    __shared__ __align__(16) float h_s[D_H];

    if (tid < 64) {
        const float4* i4 = (const float4*)&interp[a * (D_M * N_HEADS) + tid * 8];
        float4 v0 = i4[0], v1 = i4[1];
        float v[8] = {v0.x, v0.y, v0.z, v0.w, v1.x, v1.y, v1.z, v1.w};
        #pragma unroll
        for (int s = 1; s < 64; s <<= 1) {
            #pragma unroll
            for (int j = 0; j < 8; j++) v[j] += __shfl_xor(v[j], s);
        }
        if (tid == 0) {
            #pragma unroll
            for (int j = 0; j < 8; j++) isum_s[j] = v[j];
        }
    } else if (tid < 128) {
        col[tid - 64] = regular[(tid - 64) * ALPHA + a];
    }
    __syncthreads();

    float vattn;
    {
        const float4* p4 = (const float4*)&proj_w[tid * N_HEADS];
        float4 v0 = p4[0], v1 = p4[1];
        float sum = v0.x * isum_s[0] + v0.y * isum_s[1] + v0.z * isum_s[2]
                  + v0.w * isum_s[3] + v1.x * isum_s[4] + v1.y * isum_s[5]
                  + v1.z * isum_s[6] + v1.w * isum_s[7];
        vattn = proj_b[tid] + sum * (1.0f / 64.0f);
    }
    float vimp;
    {
        const float4* row = (const float4*)&conv_w[tid * D_M];
        const float4* c4  = (const float4*)col;
        float s0 = 0.f, s1 = 0.f, s2 = 0.f, s3 = 0.f;
        #pragma unroll
        for (int i = 0; i < D_M / 4; i++) {
            float4 r = row[i]; float4 c = c4[i];
            s0 += r.x * c.x; s1 += r.y * c.y; s2 += r.z * c.z; s3 += r.w * c.w;
        }
        vimp = conv_b[tid] + ((s0 + s1) + (s2 + s3));
    }
    c_s[tid]       = vimp;
    c_s[D_H + tid] = vattn;
    __syncthreads();

    {
        const float4* grow = (const float4*)&g1_w[tid * 2 * D_H];
        const float4* c4 = (const float4*)c_s;
        float s0 = 0.f, s1 = 0.f, s2 = 0.f, s3 = 0.f;
        #pragma unroll 8
        for (int i = 0; i < (2 * D_H) / 4; i++) {
            float4 g = grow[i]; float4 c = c4[i];
            s0 += g.x * c.x; s1 += g.y * c.y; s2 += g.z * c.z; s3 += g.w * c.w;
        }
        float hid = g1_b[tid] + ((s0 + s1) + (s2 + s3));
        h_s[tid] = fmaxf(hid, 0.0f);
    }
    __syncthreads();
    {
        const float4* grow = (const float4*)&g2_w[tid * D_H];
        const float4* h4 = (const float4*)h_s;
        float s0 = 0.f, s1 = 0.f, s2 = 0.f, s3 = 0.f;
        #pragma unroll 8
        for (int i = 0; i < D_H / 4; i++) {
            float4 g = grow[i]; float4 hh = h4[i];
            s0 += g.x * hh.x; s1 += g.y * hh.y; s2 += g.z * hh.z; s3 += g.w * hh.w;
        }
        float z = g2_b[tid] + ((s0 + s1) + (s2 + s3));
        float gate = 1.0f / (1.0f + __expf(-z));
        out[a * D_H + tid] = gate * vimp + (1.0f - gate) * vattn;
    }
}

// ---------------------------------------------------------------------------
extern "C" void kernel_launch(void* const* d_in, const int* in_sizes, int n_in,
                              void* d_out, int out_size, void* d_ws, size_t ws_size,
                              hipStream_t stream)
{
    (void)in_sizes; (void)n_in; (void)out_size; (void)ws_size;

    const float* x_ts    = (const float*)d_in[0];
    const float* t_ts    = (const float*)d_in[1];
    const float* gm      = (const float*)d_in[2];
    const float* conv_w  = (const float*)d_in[3];
    const float* conv_b  = (const float*)d_in[4];
    const float* t2v_w   = (const float*)d_in[5];
    const float* t2v_phi = (const float*)d_in[6];
    const float* wq_w    = (const float*)d_in[7];
    const float* wq_b    = (const float*)d_in[8];
    const float* wk_w    = (const float*)d_in[9];
    const float* proj_w  = (const float*)d_in[11];
    const float* proj_b  = (const float*)d_in[12];
    const float* g1_w    = (const float*)d_in[13];
    const float* g1_b    = (const float*)d_in[14];
    const float* g2_w    = (const float*)d_in[15];
    const float* g2_b    = (const float*)d_in[16];

    float* out = (float*)d_out;

    float* ws      = (float*)d_ws;
    float* regular = ws;                               // 16384
    float* QWbuf   = regular + D_M * ALPHA;            // 131072  [h][d][a]
    float* interp  = QWbuf + N_HEADS * D_V * ALPHA;    // 131072  [a][m][h]

    prep_kernel<<<D_M + 128, 256, 0, stream>>>(
        x_ts, t_ts, gm, t2v_w, t2v_phi, wq_w, wq_b, wk_w, regular, QWbuf);
    attn_fused_kernel<<<dim3(2, D_M, N_HEADS), 128, 0, stream>>>(
        x_ts, t_ts, t2v_w, t2v_phi, QWbuf, interp);
    final_kernel<<<ALPHA, 256, 0, stream>>>(
        regular, interp, conv_w, conv_b, proj_w, proj_b,
        g1_w, g1_b, g2_w, g2_b, out);
}